// Round 4
// baseline (960.723 us; speedup 1.0000x reference)
//
#include <hip/hip_runtime.h>
#include <hip/hip_bf16.h>
#include <stdint.h>

// GATv2Conv(1028->256, heads=1, self-loops) on gfx950, fp32 in/out.
// Pipeline: prep(x->bf16 pad, W^T->bf16, degree hist) -> bf16 MFMA GEMM
// (xl|xr, fp32 acc, bf16 xf) -> scan -> scatter (CSR) -> fused per-dst
// online-softmax gather, 8-edge batched (1 wave/node).
// R4: k_gat edge-batching (breaks serial shuffle/exp chain), fused prep,
// 3-phase scan, fewer launches. R3 was k_gat-latency-bound (VALUBusy 67%,
// HBM 23%) + ~650us of prep/scan/launch overhead.

#define N_NODES 50000
#define N_EDGES 1600000
#define D_IN    1028
#define KPAD    1056   // D_IN padded to x32; xb/Wt zero-filled beyond 1028
#define D_OUT   256
#define NB      512    // xf row: cols [0,256)=xl, [256,512)=xr

#define X2B_BLOCKS  N_NODES
#define WT_BLOCKS   ((NB * KPAD + 255) / 256)         // 2112
#define HIST_BLOCKS ((N_EDGES + 255) / 256)           // 6250
#define PREP_BLOCKS (X2B_BLOCKS + WT_BLOCKS + HIST_BLOCKS)

typedef __bf16 bf16x8 __attribute__((ext_vector_type(8)));
typedef float  f32x4  __attribute__((ext_vector_type(4)));

static __device__ __forceinline__ void gl_lds16(const void* g, void* l) {
  __builtin_amdgcn_global_load_lds(
      (const __attribute__((address_space(1))) unsigned int*)g,
      (__attribute__((address_space(3))) unsigned int*)l, 16, 0, 0);
}
static __device__ __forceinline__ float bf2f(unsigned short u) {
  union { unsigned int i; float f; } c; c.i = ((unsigned int)u) << 16; return c.f;
}
static __device__ __forceinline__ unsigned short f2bf(float f) {
  union { float f; unsigned int i; } c; c.f = f;
  unsigned int r = 0x7fffu + ((c.i >> 16) & 1u);  // round-to-nearest-even
  return (unsigned short)((c.i + r) >> 16);
}

// ---------------- edge_index dtype autodetect --------------------------------
// Values < 50000: if data is int64, high word of every entry is 0.
// mode==0 -> int64, mode!=0 -> int32.
__global__ void k_mode(const unsigned int* __restrict__ ei32, int* __restrict__ mode) {
  int t = blockIdx.x * 256 + threadIdx.x;  // 2048 probes
  if (t < 2048 && ei32[2 * t + 1] != 0u) atomicOr(mode, 1);
}

static __device__ __forceinline__ int load_idx(const int* ei, int md, int pos, int n) {
  int v = md ? ei[pos] : (int)((const long long*)ei)[pos];
  return v < 0 ? 0 : (v >= n ? n - 1 : v);
}

// ---------------- fused prep: x->xb bf16 | W->Wt bf16 | degree hist ----------
__global__ __launch_bounds__(256) void k_prep(const float* __restrict__ x,
    const float* __restrict__ Wl, const float* __restrict__ Wr,
    const int* __restrict__ ei, const int* __restrict__ mode,
    unsigned short* __restrict__ xb, unsigned short* __restrict__ Wt,
    int* __restrict__ deg) {
  const int b = blockIdx.x, t = threadIdx.x;
  if (b < X2B_BLOCKS) {
    // one block per node row; thread t converts fp32 k=[4t,4t+4) -> bf16
    const float* xr = x + (size_t)b * D_IN;        // row stride 4112B, 16B-aligned
    unsigned short* xo = xb + (size_t)b * KPAD;
    float4 v = *(const float4*)(xr + 4 * t);       // k 0..1023
    ushort4 o; o.x = f2bf(v.x); o.y = f2bf(v.y); o.z = f2bf(v.z); o.w = f2bf(v.w);
    *(ushort4*)(xo + 4 * t) = o;
    if (t == 0) {                                  // k 1024..1027
      float4 v2 = *(const float4*)(xr + 1024);
      ushort4 o2; o2.x = f2bf(v2.x); o2.y = f2bf(v2.y); o2.z = f2bf(v2.z); o2.w = f2bf(v2.w);
      *(ushort4*)(xo + 1024) = o2;
    } else if (t < 8) {                            // zero pad k 1028..1055
      ushort4 z = {0, 0, 0, 0};
      *(ushort4*)(xo + 1024 + 4 * t) = z;
    }
  } else if (b < X2B_BLOCKS + WT_BLOCKS) {
    int idx = (b - X2B_BLOCKS) * 256 + t;
    if (idx < NB * KPAD) {
      int k = idx / NB;        // 0..1055
      int n = idx - k * NB;    // consecutive threads -> coalesced W reads
      unsigned short v = 0;
      if (k < D_IN) v = f2bf((n < D_OUT) ? Wl[k * D_OUT + n] : Wr[k * D_OUT + (n - D_OUT)]);
      Wt[(size_t)n * KPAD + k] = v;
    }
  } else {
    int e = (b - X2B_BLOCKS - WT_BLOCKS) * 256 + t;
    if (e < N_EDGES) {
      int d = load_idx(ei, *mode, N_EDGES + e, N_NODES);
      atomicAdd(&deg[d], 1);
    }
  }
}

// ---------------- GEMM: xf[M][512] = xb[M][.] @ Wt^T (bf16 MFMA, bf16 out) ---
// 128x128 tile, BK=32, 16x16x32 mfma, 4 waves each 64x64.
__global__ __launch_bounds__(256) void k_gemm(const unsigned short* __restrict__ xb,
                                              const unsigned short* __restrict__ Wt,
                                              unsigned short* __restrict__ xf, int M) {
  __shared__ unsigned short As[128 * 32];  // [m][k], 32 bf16 (64B) per row
  __shared__ unsigned short Bs[128 * 32];  // [n][k]
  const int tid = threadIdx.x;
  const int w = tid >> 6, lane = tid & 63;
  const int m0 = blockIdx.x * 128, n0 = blockIdx.y * 128;
  const int wm = (w >> 1) * 64, wn = (w & 1) * 64;

  f32x4 zero = {0.f, 0.f, 0.f, 0.f};
  f32x4 acc[4][4];
#pragma unroll
  for (int i = 0; i < 4; ++i)
#pragma unroll
    for (int j = 0; j < 4; ++j) acc[i][j] = zero;

  const int lrow = lane >> 2, lch = lane & 3;  // 16 rows x 4 x16B chunks / call

  for (int k0 = 0; k0 < KPAD; k0 += 32) {
    __syncthreads();
#pragma unroll
    for (int j = 0; j < 2; ++j) {
      int gm = m0 + w * 32 + j * 16 + lrow;
      if (gm >= M) gm = M - 1;
      const char* g = (const char*)xb + ((size_t)gm * KPAD + k0) * 2 + lch * 16;
      gl_lds16(g, &As[(w * 32 + j * 16) * 32]);
    }
#pragma unroll
    for (int j = 0; j < 2; ++j) {
      int gn = n0 + w * 32 + j * 16 + lrow;
      const char* g = (const char*)Wt + ((size_t)gn * KPAD + k0) * 2 + lch * 16;
      gl_lds16(g, &Bs[(w * 32 + j * 16) * 32]);
    }
    __syncthreads();

    bf16x8 af[4], bfr[4];
#pragma unroll
    for (int t = 0; t < 4; ++t)
      af[t] = *(const bf16x8*)&As[(wm + t * 16 + (lane & 15)) * 32 + (lane >> 4) * 8];
#pragma unroll
    for (int t = 0; t < 4; ++t)
      bfr[t] = *(const bf16x8*)&Bs[(wn + t * 16 + (lane & 15)) * 32 + (lane >> 4) * 8];
#pragma unroll
    for (int mt = 0; mt < 4; ++mt)
#pragma unroll
      for (int nt = 0; nt < 4; ++nt)
        acc[mt][nt] = __builtin_amdgcn_mfma_f32_16x16x32_bf16(af[mt], bfr[nt], acc[mt][nt], 0, 0, 0);
  }

  // C/D layout: col = lane&15, row = (lane>>4)*4 + r
  const int col = lane & 15, rq = (lane >> 4) * 4;
#pragma unroll
  for (int mt = 0; mt < 4; ++mt)
#pragma unroll
    for (int nt = 0; nt < 4; ++nt)
#pragma unroll
      for (int r = 0; r < 4; ++r) {
        int m = m0 + wm + mt * 16 + rq + r;
        if (m < M) xf[(size_t)m * NB + (n0 + wn + nt * 16 + col)] = f2bf(acc[mt][nt][r]);
      }
}

// ---------------- 3-phase single-block exclusive scan (n=50000) --------------
__global__ __launch_bounds__(1024) void k_scan(const int* __restrict__ deg,
    int* __restrict__ rowstart, int* __restrict__ cursor, int n) {
  const int t = (int)threadIdx.x;
  const int lane = t & 63, wid = t >> 6;
  const int seg = (n + 1023) / 1024;   // 49
  const int base = t * seg;
  __shared__ int wsum[16];

  int sum = 0;
  for (int j = 0; j < seg; ++j) { int i = base + j; if (i < n) sum += deg[i]; }

  int x = sum;                                    // wave inclusive scan
#pragma unroll
  for (int off = 1; off < 64; off <<= 1) {
    int y = __shfl_up(x, off, 64);
    if (lane >= off) x += y;
  }
  if (lane == 63) wsum[wid] = x;
  __syncthreads();
  if (t < 16) {                                   // exclusive scan of 16 wave sums
    int v = wsum[t], s = v;
#pragma unroll
    for (int off = 1; off < 16; off <<= 1) {
      int y = __shfl_up(s, off, 16);
      if (t >= off) s += y;
    }
    wsum[t] = s - v;
  }
  __syncthreads();
  int run = wsum[wid] + (x - sum);                // exclusive prefix for thread t
  for (int j = 0; j < seg; ++j) {
    int i = base + j;
    if (i < n) { rowstart[i] = run; cursor[i] = run; run += deg[i]; }
  }
  if (t == 1023) rowstart[n] = run;
}

__global__ void k_scatter(const int* __restrict__ ei, const int* __restrict__ mode,
                          int* __restrict__ cursor, int* __restrict__ ssrc) {
  int e = blockIdx.x * blockDim.x + threadIdx.x;
  if (e < N_EDGES) {
    int md = *mode;
    int s = load_idx(ei, md, e, N_NODES);
    int d = load_idx(ei, md, N_EDGES + e, N_NODES);
    int pos = atomicAdd(&cursor[d], 1);
    if (pos >= 0 && pos < N_EDGES) ssrc[pos] = s;
  }
}

// ---------------- fused gather + online softmax + aggregate (batch-8) --------
static __device__ __forceinline__ float4 load_bf4(const unsigned short* p) {
  ushort4 u = *(const ushort4*)p;
  float4 f; f.x = bf2f(u.x); f.y = bf2f(u.y); f.z = bf2f(u.z); f.w = bf2f(u.w);
  return f;
}
static __device__ __forceinline__ float part4(float4 v, float4 xr, float4 a) {
  float t0 = v.x + xr.x; t0 = t0 > 0.f ? t0 : 0.2f * t0;
  float t1 = v.y + xr.y; t1 = t1 > 0.f ? t1 : 0.2f * t1;
  float t2 = v.z + xr.z; t2 = t2 > 0.f ? t2 : 0.2f * t2;
  float t3 = v.w + xr.w; t3 = t3 > 0.f ? t3 : 0.2f * t3;
  return fmaf(a.x, t0, fmaf(a.y, t1, fmaf(a.z, t2, a.w * t3)));
}

__global__ __launch_bounds__(256) void k_gat(const unsigned short* __restrict__ xf,
    const int* __restrict__ rowstart, const int* __restrict__ ssrc,
    const float* __restrict__ att, const float* __restrict__ bias,
    float* __restrict__ out, int n) {
  const int gw = (int)blockIdx.x * 4 + (int)(threadIdx.x >> 6);  // 1 wave/dst
  const int lane = (int)(threadIdx.x & 63);
  if (gw >= n) return;

  const float4 a = ((const float4*)att)[lane];
  float4 xr = load_bf4(xf + (size_t)gw * NB + D_OUT + 4 * lane);

  // self-loop first (guarantees nonempty segment)
  float4 xl = load_bf4(xf + (size_t)gw * NB + 4 * lane);
  float m;
  {
    float p = part4(xl, xr, a);
#pragma unroll
    for (int off = 32; off > 0; off >>= 1) p += __shfl_xor(p, off, 64);
    m = p;
  }
  float l = 1.f;
  float4 acc = xl;

  const int end = rowstart[gw + 1];
  for (int i = rowstart[gw]; i < end; i += 8) {
    float4 v[8];
    float pe[8];
#pragma unroll
    for (int j = 0; j < 8; ++j) {
      int idx = i + j;
      int sj = (idx < end) ? ssrc[idx] : gw;   // pad with self row (finite)
      sj = sj < 0 ? 0 : (sj >= n ? n - 1 : sj);
      v[j] = load_bf4(xf + (size_t)sj * NB + 4 * lane);
    }
#pragma unroll
    for (int j = 0; j < 8; ++j) pe[j] = part4(v[j], xr, a);
    // 8 independent butterfly reductions, pipelined per level
#pragma unroll
    for (int off = 32; off > 0; off >>= 1)
#pragma unroll
      for (int j = 0; j < 8; ++j) pe[j] += __shfl_xor(pe[j], off, 64);
#pragma unroll
    for (int j = 0; j < 8; ++j) if (i + j >= end) pe[j] = -1e30f;

    float mb = pe[0];
#pragma unroll
    for (int j = 1; j < 8; ++j) mb = fmaxf(mb, pe[j]);
    float mn = fmaxf(m, mb);
    float sc = __expf(m - mn);
    float psum = 0.f;
    float4 va = {0.f, 0.f, 0.f, 0.f};
#pragma unroll
    for (int j = 0; j < 8; ++j) {
      float p = __expf(pe[j] - mn);
      psum += p;
      va.x = fmaf(p, v[j].x, va.x);
      va.y = fmaf(p, v[j].y, va.y);
      va.z = fmaf(p, v[j].z, va.z);
      va.w = fmaf(p, v[j].w, va.w);
    }
    acc.x = fmaf(acc.x, sc, va.x);
    acc.y = fmaf(acc.y, sc, va.y);
    acc.z = fmaf(acc.z, sc, va.z);
    acc.w = fmaf(acc.w, sc, va.w);
    l = fmaf(l, sc, psum);
    m = mn;
  }

  float inv = 1.f / l;
  const float4 b = ((const float4*)bias)[lane];
  float4 o;
  o.x = fmaf(acc.x, inv, b.x);
  o.y = fmaf(acc.y, inv, b.y);
  o.z = fmaf(acc.z, inv, b.z);
  o.w = fmaf(acc.w, inv, b.w);
  ((float4*)out)[(size_t)gw * 64 + lane] = o;
}

// ---------------- launch -----------------------------------------------------
extern "C" void kernel_launch(void* const* d_in, const int* in_sizes, int n_in,
                              void* d_out, int out_size, void* d_ws, size_t ws_size,
                              hipStream_t stream) {
  (void)in_sizes; (void)n_in; (void)out_size; (void)ws_size;
  const float* x   = (const float*)d_in[0];
  const int*   ei  = (const int*)d_in[1];
  const float* Wl  = (const float*)d_in[2];
  const float* Wr  = (const float*)d_in[3];
  const float* att = (const float*)d_in[4];
  const float* bia = (const float*)d_in[5];
  float* out = (float*)d_out;

  const int N = N_NODES;
  const int E = N_EDGES;

  char* ws = (char*)d_ws;
  size_t off = 0;
  unsigned short* xb = (unsigned short*)(ws + off); off += (size_t)N * KPAD * 2;  // 105.6 MB
  unsigned short* xf = (unsigned short*)(ws + off); off += (size_t)N * NB * 2;    //  51.2 MB
  unsigned short* Wt = (unsigned short*)(ws + off); off += (size_t)NB * KPAD * 2; //   1.1 MB
  off = (off + 255) & ~(size_t)255;
  int* deg      = (int*)(ws + off); off += (size_t)N * 4;
  int* mode     = (int*)(ws + off); off += 256;   // adjacent to deg: one memset
  int* rowstart = (int*)(ws + off); off += (size_t)(N + 1) * 4;
  off = (off + 255) & ~(size_t)255;
  int* cursor   = (int*)(ws + off); off += (size_t)N * 4;
  int* ssrc     = (int*)(ws + off); off += (size_t)E * 4;   // total ~165 MB

  hipMemsetAsync(deg, 0, (size_t)N * 4 + 256, stream);      // deg + mode
  k_mode<<<8, 256, 0, stream>>>((const unsigned int*)ei, mode);
  k_prep<<<PREP_BLOCKS, 256, 0, stream>>>(x, Wl, Wr, ei, mode, xb, Wt, deg);
  k_gemm<<<dim3((N + 127) / 128, NB / 128), 256, 0, stream>>>(xb, Wt, xf, N);
  k_scan<<<1, 1024, 0, stream>>>(deg, rowstart, cursor, N);
  k_scatter<<<(E + 255) / 256, 256, 0, stream>>>(ei, mode, cursor, ssrc);
  k_gat<<<(N + 3) / 4, 256, 0, stream>>>(xf, rowstart, ssrc, att, bia, out, N);
}

// Round 5
// 836.279 us; speedup vs baseline: 1.1488x; 1.1488x over previous
//
#include <hip/hip_runtime.h>
#include <hip/hip_bf16.h>
#include <stdint.h>

// GATv2Conv(1028->256, heads=1, self-loops) on gfx950, fp32 in/out.
// Pipeline: prep(x->bf16 pad, W^T->bf16, degree hist) -> bf16 MFMA GEMM
// (xl|xr, fp32 acc, bf16 xf, LDS-coalesced epilogue) -> scan -> scatter (CSR)
// -> fused per-dst online-softmax gather: 2x32-lane groups per wave, 8 dims
// per lane, depth-2 gather pipeline, flash-style group merge.
// R5: R4's batch-8 regressed (VGPR 56, occupancy 38%) -> split-wave design
// keeps VGPR ~50 while serving 2 edges per instruction; GEMM epilogue was
// 64x 2B scalar stores per lane -> LDS bounce + dwordx4.

#define N_NODES 50000
#define N_EDGES 1600000
#define D_IN    1028
#define KPAD    1056   // D_IN padded to x32; xb/Wt zero-filled beyond 1028
#define D_OUT   256
#define NB      512    // xf row: cols [0,256)=xl, [256,512)=xr

#define X2B_BLOCKS  N_NODES
#define WT_BLOCKS   ((NB * KPAD + 255) / 256)         // 2112
#define HIST_BLOCKS ((N_EDGES + 255) / 256)           // 6250
#define PREP_BLOCKS (X2B_BLOCKS + WT_BLOCKS + HIST_BLOCKS)

typedef __bf16 bf16x8 __attribute__((ext_vector_type(8)));
typedef float  f32x4  __attribute__((ext_vector_type(4)));

static __device__ __forceinline__ void gl_lds16(const void* g, void* l) {
  __builtin_amdgcn_global_load_lds(
      (const __attribute__((address_space(1))) unsigned int*)g,
      (__attribute__((address_space(3))) unsigned int*)l, 16, 0, 0);
}
static __device__ __forceinline__ float bf2f(unsigned short u) {
  union { unsigned int i; float f; } c; c.i = ((unsigned int)u) << 16; return c.f;
}
static __device__ __forceinline__ unsigned short f2bf(float f) {
  union { float f; unsigned int i; } c; c.f = f;
  unsigned int r = 0x7fffu + ((c.i >> 16) & 1u);  // round-to-nearest-even
  return (unsigned short)((c.i + r) >> 16);
}

// ---------------- edge_index dtype autodetect --------------------------------
// Values < 50000: if data is int64, high word of every entry is 0.
// mode==0 -> int64, mode!=0 -> int32.
__global__ void k_mode(const unsigned int* __restrict__ ei32, int* __restrict__ mode) {
  int t = blockIdx.x * 256 + threadIdx.x;  // 2048 probes
  if (t < 2048 && ei32[2 * t + 1] != 0u) atomicOr(mode, 1);
}

static __device__ __forceinline__ int load_idx(const int* ei, int md, int pos, int n) {
  int v = md ? ei[pos] : (int)((const long long*)ei)[pos];
  return v < 0 ? 0 : (v >= n ? n - 1 : v);
}

// ---------------- fused prep: x->xb bf16 | W->Wt bf16 | degree hist ----------
__global__ __launch_bounds__(256) void k_prep(const float* __restrict__ x,
    const float* __restrict__ Wl, const float* __restrict__ Wr,
    const int* __restrict__ ei, const int* __restrict__ mode,
    unsigned short* __restrict__ xb, unsigned short* __restrict__ Wt,
    int* __restrict__ deg) {
  const int b = blockIdx.x, t = threadIdx.x;
  if (b < X2B_BLOCKS) {
    // one block per node row; thread t converts fp32 k=[4t,4t+4) -> bf16
    const float* xr = x + (size_t)b * D_IN;        // row stride 4112B, 16B-aligned
    unsigned short* xo = xb + (size_t)b * KPAD;
    float4 v = *(const float4*)(xr + 4 * t);       // k 0..1023
    ushort4 o; o.x = f2bf(v.x); o.y = f2bf(v.y); o.z = f2bf(v.z); o.w = f2bf(v.w);
    *(ushort4*)(xo + 4 * t) = o;
    if (t == 0) {                                  // k 1024..1027
      float4 v2 = *(const float4*)(xr + 1024);
      ushort4 o2; o2.x = f2bf(v2.x); o2.y = f2bf(v2.y); o2.z = f2bf(v2.z); o2.w = f2bf(v2.w);
      *(ushort4*)(xo + 1024) = o2;
    } else if (t < 8) {                            // zero pad k 1028..1055
      ushort4 z = {0, 0, 0, 0};
      *(ushort4*)(xo + 1024 + 4 * t) = z;
    }
  } else if (b < X2B_BLOCKS + WT_BLOCKS) {
    int idx = (b - X2B_BLOCKS) * 256 + t;
    if (idx < NB * KPAD) {
      int k = idx / NB;        // 0..1055
      int n = idx - k * NB;    // consecutive threads -> coalesced W reads
      unsigned short v = 0;
      if (k < D_IN) v = f2bf((n < D_OUT) ? Wl[k * D_OUT + n] : Wr[k * D_OUT + (n - D_OUT)]);
      Wt[(size_t)n * KPAD + k] = v;
    }
  } else {
    int e = (b - X2B_BLOCKS - WT_BLOCKS) * 256 + t;
    if (e < N_EDGES) {
      int d = load_idx(ei, *mode, N_EDGES + e, N_NODES);
      atomicAdd(&deg[d], 1);
    }
  }
}

// ---------------- GEMM: xf[M][512] = xb[M][.] @ Wt^T (bf16 MFMA, bf16 out) ---
// 128x128 tile, BK=32, 16x16x32 mfma, 4 waves each 64x64.
// Epilogue: C tile -> LDS (padded) -> coalesced dwordx4 stores.
__global__ __launch_bounds__(256) void k_gemm(const unsigned short* __restrict__ xb,
                                              const unsigned short* __restrict__ Wt,
                                              unsigned short* __restrict__ xf, int M) {
  __shared__ unsigned short smem[16896];  // As[0,4096) Bs[4096,8192); Cs overlays (128x132)
  unsigned short* As = smem;
  unsigned short* Bs = smem + 4096;
  unsigned short* Cs = smem;
  const int tid = threadIdx.x;
  const int w = tid >> 6, lane = tid & 63;
  const int m0 = blockIdx.x * 128, n0 = blockIdx.y * 128;
  const int wm = (w >> 1) * 64, wn = (w & 1) * 64;

  f32x4 zero = {0.f, 0.f, 0.f, 0.f};
  f32x4 acc[4][4];
#pragma unroll
  for (int i = 0; i < 4; ++i)
#pragma unroll
    for (int j = 0; j < 4; ++j) acc[i][j] = zero;

  const int lrow = lane >> 2, lch = lane & 3;  // 16 rows x 4 x16B chunks / call

  for (int k0 = 0; k0 < KPAD; k0 += 32) {
    __syncthreads();
#pragma unroll
    for (int j = 0; j < 2; ++j) {
      int gm = m0 + w * 32 + j * 16 + lrow;
      if (gm >= M) gm = M - 1;
      const char* g = (const char*)xb + ((size_t)gm * KPAD + k0) * 2 + lch * 16;
      gl_lds16(g, &As[(w * 32 + j * 16) * 32]);
    }
#pragma unroll
    for (int j = 0; j < 2; ++j) {
      int gn = n0 + w * 32 + j * 16 + lrow;
      const char* g = (const char*)Wt + ((size_t)gn * KPAD + k0) * 2 + lch * 16;
      gl_lds16(g, &Bs[(w * 32 + j * 16) * 32]);
    }
    __syncthreads();

    bf16x8 af[4], bfr[4];
#pragma unroll
    for (int t = 0; t < 4; ++t)
      af[t] = *(const bf16x8*)&As[(wm + t * 16 + (lane & 15)) * 32 + (lane >> 4) * 8];
#pragma unroll
    for (int t = 0; t < 4; ++t)
      bfr[t] = *(const bf16x8*)&Bs[(wn + t * 16 + (lane & 15)) * 32 + (lane >> 4) * 8];
#pragma unroll
    for (int mt = 0; mt < 4; ++mt)
#pragma unroll
      for (int nt = 0; nt < 4; ++nt)
        acc[mt][nt] = __builtin_amdgcn_mfma_f32_16x16x32_bf16(af[mt], bfr[nt], acc[mt][nt], 0, 0, 0);
  }

  // C/D layout: col = lane&15, row = (lane>>4)*4 + r
  __syncthreads();  // all As/Bs reads done before Cs overlay
  {
    const int col = lane & 15, rq = (lane >> 4) * 4;
#pragma unroll
    for (int mt = 0; mt < 4; ++mt)
#pragma unroll
      for (int nt = 0; nt < 4; ++nt)
#pragma unroll
        for (int r = 0; r < 4; ++r)
          Cs[(wm + mt * 16 + rq + r) * 132 + wn + nt * 16 + col] = f2bf(acc[mt][nt][r]);
  }
  __syncthreads();
  {
    const int row = tid >> 1, half = tid & 1;  // 2 threads per row, 128B each
    int gm = m0 + row;
    if (gm < M) {
      unsigned short* dst = xf + (size_t)gm * NB + n0 + half * 64;
      const unsigned short* srcp = &Cs[row * 132 + half * 64];
#pragma unroll
      for (int j = 0; j < 8; ++j)
        *(uint4*)(dst + j * 8) = *(const uint4*)(srcp + j * 8);
    }
  }
}

// ---------------- 3-phase single-block exclusive scan (n=50000) --------------
__global__ __launch_bounds__(1024) void k_scan(const int* __restrict__ deg,
    int* __restrict__ rowstart, int* __restrict__ cursor, int n) {
  const int t = (int)threadIdx.x;
  const int lane = t & 63, wid = t >> 6;
  const int seg = (n + 1023) / 1024;   // 49
  const int base = t * seg;
  __shared__ int wsum[16];

  int sum = 0;
  for (int j = 0; j < seg; ++j) { int i = base + j; if (i < n) sum += deg[i]; }

  int x = sum;                                    // wave inclusive scan
#pragma unroll
  for (int off = 1; off < 64; off <<= 1) {
    int y = __shfl_up(x, off, 64);
    if (lane >= off) x += y;
  }
  if (lane == 63) wsum[wid] = x;
  __syncthreads();
  if (t < 16) {                                   // exclusive scan of 16 wave sums
    int v = wsum[t], s = v;
#pragma unroll
    for (int off = 1; off < 16; off <<= 1) {
      int y = __shfl_up(s, off, 16);
      if (t >= off) s += y;
    }
    wsum[t] = s - v;
  }
  __syncthreads();
  int run = wsum[wid] + (x - sum);                // exclusive prefix for thread t
  for (int j = 0; j < seg; ++j) {
    int i = base + j;
    if (i < n) { rowstart[i] = run; cursor[i] = run; run += deg[i]; }
  }
  if (t == 1023) rowstart[n] = run;
}

__global__ void k_scatter(const int* __restrict__ ei, const int* __restrict__ mode,
                          int* __restrict__ cursor, int* __restrict__ ssrc) {
  int e = blockIdx.x * blockDim.x + threadIdx.x;
  if (e < N_EDGES) {
    int md = *mode;
    int s = load_idx(ei, md, e, N_NODES);
    int d = load_idx(ei, md, N_EDGES + e, N_NODES);
    int pos = atomicAdd(&cursor[d], 1);
    if (pos >= 0 && pos < N_EDGES) ssrc[pos] = s;
  }
}

// ---------------- fused gather + online softmax + aggregate ------------------
// Wave = 2 groups x 32 lanes; lane covers dims [8*gl, 8*gl+8). Each group
// processes alternating edges of the same dst; flash-merge at the end.
static __device__ __forceinline__ void unpack8(uint4 u, float* v) {
  union { unsigned int i; float f; } c;
  c.i = u.x << 16;         v[0] = c.f;
  c.i = u.x & 0xffff0000u; v[1] = c.f;
  c.i = u.y << 16;         v[2] = c.f;
  c.i = u.y & 0xffff0000u; v[3] = c.f;
  c.i = u.z << 16;         v[4] = c.f;
  c.i = u.z & 0xffff0000u; v[5] = c.f;
  c.i = u.w << 16;         v[6] = c.f;
  c.i = u.w & 0xffff0000u; v[7] = c.f;
}
static __device__ __forceinline__ float dot8(const float* v, const float* xr, const float* a) {
  float e = 0.f;
#pragma unroll
  for (int d = 0; d < 8; ++d) {
    float t = v[d] + xr[d];
    t = fmaxf(t, 0.2f * t);        // LeakyReLU(0.2): max(t, 0.2t)
    e = fmaf(a[d], t, e);
  }
  return e;
}
static __device__ __forceinline__ float red32(float e) {
#pragma unroll
  for (int off = 1; off < 32; off <<= 1) e += __shfl_xor(e, off, 64);
  return e;
}

__global__ __launch_bounds__(256) void k_gat(const unsigned short* __restrict__ xf,
    const int* __restrict__ rowstart, const int* __restrict__ ssrc,
    const float* __restrict__ att, const float* __restrict__ bias,
    float* __restrict__ out, int n) {
  const int gw = (int)blockIdx.x * 4 + (int)(threadIdx.x >> 6);  // 1 wave/dst
  const int lane = (int)(threadIdx.x & 63);
  const int grp = lane >> 5, gl = lane & 31;
  if (gw >= n) return;

  float a[8];
  {
    float4 A0 = ((const float4*)att)[2 * gl];
    float4 A1 = ((const float4*)att)[2 * gl + 1];
    a[0] = A0.x; a[1] = A0.y; a[2] = A0.z; a[3] = A0.w;
    a[4] = A1.x; a[5] = A1.y; a[6] = A1.z; a[7] = A1.w;
  }
  float xr[8], vs[8];
  unpack8(*(const uint4*)(xf + (size_t)gw * NB + D_OUT + 8 * gl), xr);
  unpack8(*(const uint4*)(xf + (size_t)gw * NB + 8 * gl), vs);   // self row (xl)

  // self-loop into group 0; group 1 starts empty
  float m, l, acc[8];
  {
    float e = red32(dot8(vs, xr, a));
    if (grp == 0) {
      m = e; l = 1.f;
#pragma unroll
      for (int d = 0; d < 8; ++d) acc[d] = vs[d];
    } else {
      m = -1e30f; l = 0.f;
#pragma unroll
      for (int d = 0; d < 8; ++d) acc[d] = 0.f;
    }
  }

  const int end = rowstart[gw + 1];
  int i = rowstart[gw] + grp;                     // group g: edges beg+g, +2, ...
  bool have = i < end;
  uint4 vu;
  if (have) {
    unsigned s = (unsigned)ssrc[i];
    vu = *(const uint4*)(xf + ((size_t)s << 9) + 8 * gl);
  }
  while (have) {
    int i2 = i + 2;
    bool have2 = i2 < end;
    uint4 vu2;
    if (have2) {                                  // depth-2 pipeline: prefetch
      unsigned s2 = (unsigned)ssrc[i2];
      vu2 = *(const uint4*)(xf + ((size_t)s2 << 9) + 8 * gl);
    }
    float v[8];
    unpack8(vu, v);
    float e = red32(dot8(v, xr, a));
    float mn = fmaxf(m, e);
    float sc = __expf(m - mn);
    float p  = __expf(e - mn);
#pragma unroll
    for (int d = 0; d < 8; ++d) acc[d] = fmaf(p, v[d], acc[d] * sc);
    l = fmaf(l, sc, p);
    m = mn;
    vu = vu2; i = i2; have = have2;
  }

  // flash-merge the two groups (lane L and L+32 hold the same dims)
  float mo = __shfl_xor(m, 32, 64);
  float mM = fmaxf(m, mo);
  float sA = __expf(m - mM);
  float lA = l * sA;
  float lS = lA + __shfl_xor(lA, 32, 64);
  float inv = 1.f / lS;
#pragma unroll
  for (int d = 0; d < 8; ++d) {
    float t = acc[d] * sA;
    acc[d] = t + __shfl_xor(t, 32, 64);
  }
  if (grp == 0) {
    float4 B0 = ((const float4*)bias)[2 * gl];
    float4 B1 = ((const float4*)bias)[2 * gl + 1];
    float4 o0, o1;
    o0.x = fmaf(acc[0], inv, B0.x); o0.y = fmaf(acc[1], inv, B0.y);
    o0.z = fmaf(acc[2], inv, B0.z); o0.w = fmaf(acc[3], inv, B0.w);
    o1.x = fmaf(acc[4], inv, B1.x); o1.y = fmaf(acc[5], inv, B1.y);
    o1.z = fmaf(acc[6], inv, B1.z); o1.w = fmaf(acc[7], inv, B1.w);
    ((float4*)out)[(size_t)gw * 64 + 2 * gl] = o0;
    ((float4*)out)[(size_t)gw * 64 + 2 * gl + 1] = o1;
  }
}

// ---------------- launch -----------------------------------------------------
extern "C" void kernel_launch(void* const* d_in, const int* in_sizes, int n_in,
                              void* d_out, int out_size, void* d_ws, size_t ws_size,
                              hipStream_t stream) {
  (void)in_sizes; (void)n_in; (void)out_size; (void)ws_size;
  const float* x   = (const float*)d_in[0];
  const int*   ei  = (const int*)d_in[1];
  const float* Wl  = (const float*)d_in[2];
  const float* Wr  = (const float*)d_in[3];
  const float* att = (const float*)d_in[4];
  const float* bia = (const float*)d_in[5];
  float* out = (float*)d_out;

  const int N = N_NODES;
  const int E = N_EDGES;

  char* ws = (char*)d_ws;
  size_t off = 0;
  unsigned short* xb = (unsigned short*)(ws + off); off += (size_t)N * KPAD * 2;  // 105.6 MB
  unsigned short* xf = (unsigned short*)(ws + off); off += (size_t)N * NB * 2;    //  51.2 MB
  unsigned short* Wt = (unsigned short*)(ws + off); off += (size_t)NB * KPAD * 2; //   1.1 MB
  off = (off + 255) & ~(size_t)255;
  int* deg      = (int*)(ws + off); off += (size_t)N * 4;
  int* mode     = (int*)(ws + off); off += 256;   // adjacent to deg: one memset
  int* rowstart = (int*)(ws + off); off += (size_t)(N + 1) * 4;
  off = (off + 255) & ~(size_t)255;
  int* cursor   = (int*)(ws + off); off += (size_t)N * 4;
  int* ssrc     = (int*)(ws + off); off += (size_t)E * 4;   // total ~165 MB

  hipMemsetAsync(deg, 0, (size_t)N * 4 + 256, stream);      // deg + mode
  k_mode<<<8, 256, 0, stream>>>((const unsigned int*)ei, mode);
  k_prep<<<PREP_BLOCKS, 256, 0, stream>>>(x, Wl, Wr, ei, mode, xb, Wt, deg);
  k_gemm<<<dim3((N + 127) / 128, NB / 128), 256, 0, stream>>>(xb, Wt, xf, N);
  k_scan<<<1, 1024, 0, stream>>>(deg, rowstart, cursor, N);
  k_scatter<<<(E + 255) / 256, 256, 0, stream>>>(ei, mode, cursor, ssrc);
  k_gat<<<(N + 3) / 4, 256, 0, stream>>>(xf, rowstart, ssrc, att, bia, out, N);
}